// Round 9
// baseline (277.018 us; speedup 1.0000x reference)
//
#include <hip/hip_runtime.h>
#include <hip/hip_bf16.h>
#include <stdint.h>

#define BATCH 4096
#define TLEN  1024
#define MSTR  72     // LDS stride (bf16 elems) for T matrices; 144B keeps b64/b128 alignment

// ---- LDS layout (bytes) ----
#define OFF_T    0        // Tsm plain [64][MSTR] bf16   (bwd A source)
#define OFF_G    9216     // Tsm^T     [64][MSTR] bf16   (fwd A source)
#define OFF_PE   18432    // float pE[2][64]
#define OFF_PIV  18944    // float piv[64]
#define OFF_YB   19200    // u64 yball[16][16] = 2048
#define OFF_YSF  21248    // u64 ybsF[8 words][64 lanes] = 4096
#define OFF_YSB  25344    // u64 ybsB[8 words][64 lanes] = 4096
#define SMEM_SZ  29440

typedef short        bf16x4 __attribute__((ext_vector_type(4)));
typedef short        bf16x8 __attribute__((ext_vector_type(8)));
typedef float        f32x4  __attribute__((ext_vector_type(4)));
typedef unsigned int u32;
typedef unsigned int u32x4  __attribute__((ext_vector_type(4)));

#define MFMA(a,b,c) __builtin_amdgcn_mfma_f32_16x16x32_bf16(a,b,c,0,0,0)

// Hardware packed f32->2xbf16 (RNE), proven in round 7.
static __device__ __forceinline__ u32 packpair(float lo, float hi) {
    u32 r;
    asm("v_cvt_pk_bf16_f32 %0, %1, %2" : "=&v"(r) : "v"(lo), "v"(hi));
    return r;
}

// ---------------------------------------------------------------------------
// 256 wgs x 64 thr (ONE wave per wg, one wg per CU). Each wave runs BOTH
// direction-chains for its 16-batch block, interleaved in one instruction
// stream:
//   chain F: forward  alpha, A = T^T (sigma-permuted), B-side emission
//   chain B: backward gamma (gamma_t = e_t ⊙ beta_t), A = T (sigma-permuted)
// ROUND-9 RATIONALE: round-7 ledger showed 581 cy/step with only ~156 cy of
// issue — 73% dependent-issue/hazard stall at 1 chain per SIMD. Two
// independent chains in one wave fill each other's bubbles (round-4's try
// failed on a halved grid + fat code; both fixed here — grid stays 256).
// Per-chain machinery is byte-identical round 7: cvt_pk pack, register-only
// D->B repack with k-slot permutation sigma(h,g,j)=32h+4g+(j&3)+16(j>>2),
// bare-T A-frags (fwd tail reuses them), per-lane LDS bit-words,
// code-size-bounded 31x16+15 loop, renorm every 16 steps.
// Single-wave wg => NO barriers anywhere; combine is register-local.
// ---------------------------------------------------------------------------
__global__ __launch_bounds__(64, 1) void hmm_fb(
    const int* __restrict__ y, const float* __restrict__ Tmat,
    const float* __restrict__ Emat, const float* __restrict__ Pi,
    float* __restrict__ out)
{
    __shared__ __align__(16) unsigned char SM[SMEM_SZ];

    const int tid  = threadIdx.x;       // 0..63, == lane
    const int lane = tid;
    const int lr   = lane & 15;         // batch col
    const int g    = lane >> 4;         // k-group
    const int R0   = blockIdx.x << 4;

    float* pE  = (float*)(SM + OFF_PE);
    float* piv = (float*)(SM + OFF_PIV);
    const f32x4 zero = {0.f, 0.f, 0.f, 0.f};

    // ---- phase 0: emission + pi softmax (whole wave = 64 lanes) ----
    {
        const float e0 = Emat[tid*2+0], e1 = Emat[tid*2+1];
        const float em = fmaxf(e0, e1);
        const float p0 = __expf(e0-em), p1 = __expf(e1-em);
        const float ez = 1.0f / (p0 + p1);
        pE[tid]      = p0 * ez;
        pE[64 + tid] = p1 * ez;
        float v = Pi[tid];
        float mx = v;
        #pragma unroll
        for (int d = 1; d < 64; d <<= 1) mx = fmaxf(mx, __shfl_xor(mx, d));
        const float e = __expf(v - mx);
        float z = e;
        #pragma unroll
        for (int d = 1; d < 64; d <<= 1) z += __shfl_xor(z, d);
        piv[tid] = e / z;
    }

    // ---- phase 1: row-softmax of T; one full row per lane (no shuffles) ----
    {
        const int r = tid;                // row 0..63
        float v[64];
        #pragma unroll
        for (int q = 0; q < 16; q++) {
            const float4 t4 = *(const float4*)(Tmat + r*64 + q*4);
            v[q*4+0]=t4.x; v[q*4+1]=t4.y; v[q*4+2]=t4.z; v[q*4+3]=t4.w;
        }
        float mx = v[0];
        #pragma unroll
        for (int k = 1; k < 64; k++) mx = fmaxf(mx, v[k]);
        float z = 0.f;
        #pragma unroll
        for (int k = 0; k < 64; k++) { v[k] = __expf(v[k]-mx); z += v[k]; }
        const float inv = 1.0f / z;
        __hip_bfloat16* Tsm = (__hip_bfloat16*)(SM + OFF_T);
        __hip_bfloat16* Gt  = (__hip_bfloat16*)(SM + OFF_G);
        #pragma unroll
        for (int k = 0; k < 64; k++) {
            const __hip_bfloat16 hb = __float2bfloat16(v[k] * inv);
            Tsm[r*MSTR + k] = hb;     // Tsm[s][s']
            Gt[k*MSTR + r]  = hb;     // Gt[s'][s] = T[s][s']
        }
    }
    // single-wave wg: ds_write->ds_read ordered by lgkmcnt; no barrier needed

    // ---- phase 2: gather permuted A-fragments for BOTH chains ----
    // A[m][h] element j (lane g): col sigma = 32h + 4g + (j&3) + 16*(j>>2)
    bf16x8 F00,F01,F10,F11,F20,F21,F30,F31;   // fwd: from Gt (T^T)
    bf16x8 B00,B01,B10,B11,B20,B21,B30,B31;   // bwd: from Tsm (T)
    {
        const __hip_bfloat16* Gb = (const __hip_bfloat16*)(SM + OFF_G);
        const __hip_bfloat16* Tb = (const __hip_bfloat16*)(SM + OFF_T);
        #define LDFRAG(dst, base, m, h) { \
            const __hip_bfloat16* p_ = (base) + ((m)*16+lr)*MSTR + 32*(h) + 4*g; \
            bf16x4 lo_ = *(const bf16x4*)(p_); \
            bf16x4 hi_ = *(const bf16x4*)(p_ + 16); \
            dst[0]=lo_[0]; dst[1]=lo_[1]; dst[2]=lo_[2]; dst[3]=lo_[3]; \
            dst[4]=hi_[0]; dst[5]=hi_[1]; dst[6]=hi_[2]; dst[7]=hi_[3]; \
        }
        LDFRAG(F00,Gb,0,0); LDFRAG(F01,Gb,0,1); LDFRAG(F10,Gb,1,0); LDFRAG(F11,Gb,1,1);
        LDFRAG(F20,Gb,2,0); LDFRAG(F21,Gb,2,1); LDFRAG(F30,Gb,3,0); LDFRAG(F31,Gb,3,1);
        LDFRAG(B00,Tb,0,0); LDFRAG(B01,Tb,0,1); LDFRAG(B10,Tb,1,0); LDFRAG(B11,Tb,1,1);
        LDFRAG(B20,Tb,2,0); LDFRAG(B21,Tb,2,1); LDFRAG(B30,Tb,3,0); LDFRAG(B31,Tb,3,1);
        #undef LDFRAG
    }

    // ---- phase 3: ballot-pack y into LDS words (all 16 rows) ----
    unsigned long long* yball = (unsigned long long*)(SM + OFF_YB);
    #pragma unroll
    for (int q = 0; q < 16; q++) {
        const int* yr = y + (size_t)(R0 + q) * TLEN;
        #pragma unroll
        for (int w = 0; w < 16; w++) {
            const unsigned long long bal = __ballot(yr[w*64 + lane] != 0);
            if (lane == 0) yball[q*16 + w] = bal;
        }
    }

    // ---- phase 4: per-lane bit-streams for BOTH chains -> per-lane LDS ----
    // F stream bit s: y[s+1] (s=0..510); B stream bit s: y[1022-s]
    unsigned long long* ybsF = (unsigned long long*)(SM + OFF_YSF);
    unsigned long long* ybsB = (unsigned long long*)(SM + OFF_YSB);
    int initF, initB;
    {
        unsigned long long rawF[8], rawB[8];
        #pragma unroll
        for (int w = 0; w < 8; w++) {
            rawF[w] = yball[lr*16 + w];
            rawB[w] = __brevll(yball[lr*16 + (15-w)]);
        }
        initF = (int)(rawF[0] & 1ull);            // y[0]
        initB = (int)(rawB[0] & 1ull);            // y[1023]
        #pragma unroll
        for (int w = 0; w < 7; w++) {
            ybsF[w*64 + lane] = (rawF[w] >> 1) | (rawF[w+1] << 63);
            ybsB[w*64 + lane] = (rawB[w] >> 1) | (rawB[w+1] << 63);
        }
        ybsF[7*64 + lane] = rawF[7] >> 1;
        ybsB[7*64 + lane] = rawB[7] >> 1;
    }
    // Each lane reads back ONLY its own slots (same-wave write->read).

    const f32x4 e0_0 = *(const f32x4*)(pE +       0 + 4*g);
    const f32x4 e0_1 = *(const f32x4*)(pE +      16 + 4*g);
    const f32x4 e0_2 = *(const f32x4*)(pE +      32 + 4*g);
    const f32x4 e0_3 = *(const f32x4*)(pE +      48 + 4*g);
    const f32x4 e1_0 = *(const f32x4*)(pE + 64 +  0 + 4*g);
    const f32x4 e1_1 = *(const f32x4*)(pE + 64 + 16 + 4*g);
    const f32x4 e1_2 = *(const f32x4*)(pE + 64 + 32 + 4*g);
    const f32x4 e1_3 = *(const f32x4*)(pE + 64 + 48 + 4*g);

    // ---- init both chains ----
    f32x4 dF0,dF1,dF2,dF3, dB0,dB1,dB2,dB3;
    {
        const f32x4 p0 = *(const f32x4*)(piv +  0 + 4*g);
        const f32x4 p1 = *(const f32x4*)(piv + 16 + 4*g);
        const f32x4 p2 = *(const f32x4*)(piv + 32 + 4*g);
        const f32x4 p3 = *(const f32x4*)(piv + 48 + 4*g);
        dF0 = p0 * (initF ? e1_0 : e0_0);         // alpha_0 = piv ⊙ e_{y0}
        dF1 = p1 * (initF ? e1_1 : e0_1);
        dF2 = p2 * (initF ? e1_2 : e0_2);
        dF3 = p3 * (initF ? e1_3 : e0_3);
        dB0 = initB ? e1_0 : e0_0;                // gamma_1023 = e_{y1023}
        dB1 = initB ? e1_1 : e0_1;
        dB2 = initB ? e1_2 : e0_2;
        dB3 = initB ? e1_3 : e0_3;
    }

    // ---- main loop: 511 steps, both chains interleaved in one wave ----
    f32x4 tF0,tF1,tF2,tF3, tB0,tB1,tB2,tB3;
    #define PACK(b1,b2,d0,d1,d2,d3) \
        u32x4 w1_##b1, w2_##b1; \
        w1_##b1[0] = packpair(d0.x, d0.y);  w1_##b1[1] = packpair(d0.z, d0.w); \
        w1_##b1[2] = packpair(d1.x, d1.y);  w1_##b1[3] = packpair(d1.z, d1.w); \
        w2_##b1[0] = packpair(d2.x, d2.y);  w2_##b1[1] = packpair(d2.z, d2.w); \
        w2_##b1[2] = packpair(d3.x, d3.y);  w2_##b1[3] = packpair(d3.z, d3.w); \
        const bf16x8 b1 = __builtin_bit_cast(bf16x8, w1_##b1); \
        const bf16x8 b2 = __builtin_bit_cast(bf16x8, w2_##b1);
    #define STEP_BODY() { \
        PACK(bF1, bF2, dF0, dF1, dF2, dF3); \
        PACK(bB1, bB2, dB0, dB1, dB2, dB3); \
        tF0 = MFMA(F00, bF1, zero); tF1 = MFMA(F10, bF1, zero); \
        tF2 = MFMA(F20, bF1, zero); tF3 = MFMA(F30, bF1, zero); \
        tB0 = MFMA(B00, bB1, zero); tB1 = MFMA(B10, bB1, zero); \
        tB2 = MFMA(B20, bB1, zero); tB3 = MFMA(B30, bB1, zero); \
        tF0 = MFMA(F01, bF2, tF0);  tF1 = MFMA(F11, bF2, tF1); \
        tF2 = MFMA(F21, bF2, tF2);  tF3 = MFMA(F31, bF2, tF3); \
        tB0 = MFMA(B01, bB2, tB0);  tB1 = MFMA(B11, bB2, tB1); \
        tB2 = MFMA(B21, bB2, tB2);  tB3 = MFMA(B31, bB2, tB3); }
    #define EMIT_F(cond) { \
        const bool yb_ = (cond); \
        dF0 = tF0 * (yb_ ? e1_0 : e0_0); \
        dF1 = tF1 * (yb_ ? e1_1 : e0_1); \
        dF2 = tF2 * (yb_ ? e1_2 : e0_2); \
        dF3 = tF3 * (yb_ ? e1_3 : e0_3); }
    #define EMIT_B(cond) { \
        const bool yb_ = (cond); \
        dB0 = tB0 * (yb_ ? e1_0 : e0_0); \
        dB1 = tB1 * (yb_ ? e1_1 : e0_1); \
        dB2 = tB2 * (yb_ ? e1_2 : e0_2); \
        dB3 = tB3 * (yb_ ? e1_3 : e0_3); }
    #define RENORM(t0,t1,t2,t3,lacc) { \
        float S_ = t0.x+t0.y+t0.z+t0.w + t1.x+t1.y+t1.z+t1.w \
                 + t2.x+t2.y+t2.z+t2.w + t3.x+t3.y+t3.z+t3.w; \
        S_ += __shfl_xor(S_, 16); \
        S_ += __shfl_xor(S_, 32); \
        lacc += __logf(S_); \
        const float rn_ = __builtin_amdgcn_rcpf(S_); \
        t0 *= rn_; t1 *= rn_; t2 *= rn_; t3 *= rn_; }

    float laccF = 0.f, laccB = 0.f;
    // 31 groups x 16 steps = steps 0..495; renorm at step 15 of each group.
    #pragma unroll 1
    for (int grp = 0; grp < 31; ++grp) {
        const unsigned long long cwF = ybsF[((grp >> 2) << 6) + lane];
        const unsigned long long cwB = ybsB[((grp >> 2) << 6) + lane];
        const u32 bitsF = (u32)(cwF >> ((grp & 3) << 4));
        const u32 bitsB = (u32)(cwB >> ((grp & 3) << 4));
        #pragma unroll
        for (int i = 0; i < 16; ++i) {
            STEP_BODY();
            if (i == 15) {                      // renorm every 16 steps
                RENORM(tF0,tF1,tF2,tF3, laccF);
                RENORM(tB0,tB1,tB2,tB3, laccB);
            }
            EMIT_F(((bitsF >> i) & 1u) != 0u);
            EMIT_B(((bitsB >> i) & 1u) != 0u);
        }
    }
    // tail: steps 496..510 (stream bits 48..62 of word 7), rolled
    {
        u32 bitsF = (u32)(ybsF[(7 << 6) + lane] >> 48);
        u32 bitsB = (u32)(ybsB[(7 << 6) + lane] >> 48);
        #pragma unroll 1
        for (int i = 0; i < 15; ++i) {
            STEP_BODY();
            EMIT_F((bitsF & 1u) != 0u);
            EMIT_B((bitsB & 1u) != 0u);
            bitsF >>= 1;
            bitsB >>= 1;
        }
    }

    // ---- fwd bare matvec (no emission) -> abar_512 (reuses bare T^T frags) ----
    {
        PACK(bT1, bT2, dF0, dF1, dF2, dF3);
        tF0 = MFMA(F00, bT1, zero); tF1 = MFMA(F10, bT1, zero);
        tF2 = MFMA(F20, bT1, zero); tF3 = MFMA(F30, bT1, zero);
        tF0 = MFMA(F01, bT2, tF0);  tF1 = MFMA(F11, bT2, tF1);
        tF2 = MFMA(F21, bT2, tF2);  tF3 = MFMA(F31, bT2, tF3);
        dF0 = tF0; dF1 = tF1; dF2 = tF2; dF3 = tF3;
    }
    #undef PACK
    #undef STEP_BODY
    #undef EMIT_F
    #undef EMIT_B
    #undef RENORM

    // ---- combine (register-local): logP = laccF+laccB+log(abar . gamma) ----
    {
        float dot = dF0.x*dB0.x + dF0.y*dB0.y + dF0.z*dB0.z + dF0.w*dB0.w
                  + dF1.x*dB1.x + dF1.y*dB1.y + dF1.z*dB1.z + dF1.w*dB1.w
                  + dF2.x*dB2.x + dF2.y*dB2.y + dF2.z*dB2.z + dF2.w*dB2.w
                  + dF3.x*dB3.x + dF3.y*dB3.y + dF3.z*dB3.z + dF3.w*dB3.w;
        dot += __shfl_xor(dot, 16);
        dot += __shfl_xor(dot, 32);
        float lp = laccF + laccB + __logf(dot);
        if (g == 0) {                      // lanes 0..15: reduce over batch
            lp += __shfl_xor(lp, 1);
            lp += __shfl_xor(lp, 2);
            lp += __shfl_xor(lp, 4);
            lp += __shfl_xor(lp, 8);
            if (lr == 0) atomicAdd(out, lp * (1.0f / BATCH));
        }
    }
}

// ---------------------------------------------------------------------------
extern "C" void kernel_launch(void* const* d_in, const int* in_sizes, int n_in,
                              void* d_out, int out_size, void* d_ws, size_t ws_size,
                              hipStream_t stream) {
    const int*   y  = (const int*)  d_in[0];
    const float* T  = (const float*)d_in[1];
    const float* E  = (const float*)d_in[2];
    const float* Pi = (const float*)d_in[3];
    float* out = (float*)d_out;
    (void)d_ws; (void)ws_size; (void)in_sizes; (void)n_in; (void)out_size;

    hipMemsetAsync(out, 0, sizeof(float), stream);
    hipLaunchKernelGGL(hmm_fb, dim3(BATCH/16), dim3(64), 0, stream,
                       y, T, E, Pi, out);
}

// Round 10
// 274.722 us; speedup vs baseline: 1.0084x; 1.0084x over previous
//
#include <hip/hip_runtime.h>
#include <hip/hip_bf16.h>
#include <stdint.h>

#define BATCH 4096
#define TLEN  1024
#define MSTR  72     // LDS stride (bf16 elems) for T matrices; 144B keeps b64/b128 alignment

// ---- LDS layout (bytes) ----
#define OFF_T    0        // Tsm plain [64][MSTR] bf16   (bwd A source)
#define OFF_G    9216     // Tsm^T     [64][MSTR] bf16   (fwd A source)
#define OFF_PE   18432    // float pE[2][64]
#define OFF_PIV  18944    // float piv[64]
#define OFF_YB   19200    // u64 yball[16][16] = 2048
#define OFF_YSF  21248    // u64 ybsF[8 words][64 lanes] = 4096
#define OFF_YSB  25344    // u64 ybsB[8 words][64 lanes] = 4096
#define SMEM_SZ  29440

typedef short        bf16x4 __attribute__((ext_vector_type(4)));
typedef short        bf16x8 __attribute__((ext_vector_type(8)));
typedef float        f32x4  __attribute__((ext_vector_type(4)));
typedef unsigned int u32;
typedef unsigned int u32x4  __attribute__((ext_vector_type(4)));

#define MFMA(a,b,c) __builtin_amdgcn_mfma_f32_16x16x32_bf16(a,b,c,0,0,0)

// Hardware packed f32->2xbf16 (RNE), proven in round 7.
static __device__ __forceinline__ u32 packpair(float lo, float hi) {
    u32 r;
    asm("v_cvt_pk_bf16_f32 %0, %1, %2" : "=&v"(r) : "v"(lo), "v"(hi));
    return r;
}

// ROUND-10 DELTA (the only change vs round 9): pin MFMA accumulator state
// into ARCH VGPRs. Round-9 post-mortem: VGPR_Count=100 for a ~190-reg
// 2-chain footprint => the second chain's accumulators lived in AGPRs,
// paying v_accvgpr_read/write + MFMA-read hazards every step — which ate
// exactly the ILP the fused wave was built to expose (r4 same signature,
// VGPR=92). Empty asm with "+v" (arch-VGPR-only class; AGPRs are "a")
// is a zero-instruction allocation constraint: D/C operands of the MFMA
// chain must be arch VGPRs. gfx950's unified file allows this.
#define PIN4(a,b,c,d) asm("" : "+v"(a), "+v"(b), "+v"(c), "+v"(d))

// ---------------------------------------------------------------------------
// 256 wgs x 64 thr (ONE wave per wg, one wg per CU). Each wave runs BOTH
// direction-chains for its 16-batch block, interleaved in one instruction
// stream:
//   chain F: forward  alpha, A = T^T (sigma-permuted), B-side emission
//   chain B: backward gamma (gamma_t = e_t ⊙ beta_t), A = T (sigma-permuted)
// Per-chain machinery byte-identical round 7/9: cvt_pk pack, register-only
// D->B repack with k-slot permutation sigma(h,g,j)=32h+4g+(j&3)+16(j>>2),
// bare-T A-frags (fwd tail reuses them), per-lane LDS bit-words,
// code-size-bounded 31x16+15 loop, renorm every 16 steps.
// Single-wave wg => NO barriers anywhere; combine is register-local.
// ---------------------------------------------------------------------------
__global__ __launch_bounds__(64, 1) void hmm_fb(
    const int* __restrict__ y, const float* __restrict__ Tmat,
    const float* __restrict__ Emat, const float* __restrict__ Pi,
    float* __restrict__ out)
{
    __shared__ __align__(16) unsigned char SM[SMEM_SZ];

    const int tid  = threadIdx.x;       // 0..63, == lane
    const int lane = tid;
    const int lr   = lane & 15;         // batch col
    const int g    = lane >> 4;         // k-group
    const int R0   = blockIdx.x << 4;

    float* pE  = (float*)(SM + OFF_PE);
    float* piv = (float*)(SM + OFF_PIV);
    const f32x4 zero = {0.f, 0.f, 0.f, 0.f};

    // ---- phase 0: emission + pi softmax (whole wave = 64 lanes) ----
    {
        const float e0 = Emat[tid*2+0], e1 = Emat[tid*2+1];
        const float em = fmaxf(e0, e1);
        const float p0 = __expf(e0-em), p1 = __expf(e1-em);
        const float ez = 1.0f / (p0 + p1);
        pE[tid]      = p0 * ez;
        pE[64 + tid] = p1 * ez;
        float v = Pi[tid];
        float mx = v;
        #pragma unroll
        for (int d = 1; d < 64; d <<= 1) mx = fmaxf(mx, __shfl_xor(mx, d));
        const float e = __expf(v - mx);
        float z = e;
        #pragma unroll
        for (int d = 1; d < 64; d <<= 1) z += __shfl_xor(z, d);
        piv[tid] = e / z;
    }

    // ---- phase 1: row-softmax of T; one full row per lane (no shuffles) ----
    {
        const int r = tid;                // row 0..63
        float v[64];
        #pragma unroll
        for (int q = 0; q < 16; q++) {
            const float4 t4 = *(const float4*)(Tmat + r*64 + q*4);
            v[q*4+0]=t4.x; v[q*4+1]=t4.y; v[q*4+2]=t4.z; v[q*4+3]=t4.w;
        }
        float mx = v[0];
        #pragma unroll
        for (int k = 1; k < 64; k++) mx = fmaxf(mx, v[k]);
        float z = 0.f;
        #pragma unroll
        for (int k = 0; k < 64; k++) { v[k] = __expf(v[k]-mx); z += v[k]; }
        const float inv = 1.0f / z;
        __hip_bfloat16* Tsm = (__hip_bfloat16*)(SM + OFF_T);
        __hip_bfloat16* Gt  = (__hip_bfloat16*)(SM + OFF_G);
        #pragma unroll
        for (int k = 0; k < 64; k++) {
            const __hip_bfloat16 hb = __float2bfloat16(v[k] * inv);
            Tsm[r*MSTR + k] = hb;     // Tsm[s][s']
            Gt[k*MSTR + r]  = hb;     // Gt[s'][s] = T[s][s']
        }
    }
    // single-wave wg: ds_write->ds_read ordered by lgkmcnt; no barrier needed

    // ---- phase 2: gather permuted A-fragments for BOTH chains ----
    // A[m][h] element j (lane g): col sigma = 32h + 4g + (j&3) + 16*(j>>2)
    bf16x8 F00,F01,F10,F11,F20,F21,F30,F31;   // fwd: from Gt (T^T)
    bf16x8 B00,B01,B10,B11,B20,B21,B30,B31;   // bwd: from Tsm (T)
    {
        const __hip_bfloat16* Gb = (const __hip_bfloat16*)(SM + OFF_G);
        const __hip_bfloat16* Tb = (const __hip_bfloat16*)(SM + OFF_T);
        #define LDFRAG(dst, base, m, h) { \
            const __hip_bfloat16* p_ = (base) + ((m)*16+lr)*MSTR + 32*(h) + 4*g; \
            bf16x4 lo_ = *(const bf16x4*)(p_); \
            bf16x4 hi_ = *(const bf16x4*)(p_ + 16); \
            dst[0]=lo_[0]; dst[1]=lo_[1]; dst[2]=lo_[2]; dst[3]=lo_[3]; \
            dst[4]=hi_[0]; dst[5]=hi_[1]; dst[6]=hi_[2]; dst[7]=hi_[3]; \
        }
        LDFRAG(F00,Gb,0,0); LDFRAG(F01,Gb,0,1); LDFRAG(F10,Gb,1,0); LDFRAG(F11,Gb,1,1);
        LDFRAG(F20,Gb,2,0); LDFRAG(F21,Gb,2,1); LDFRAG(F30,Gb,3,0); LDFRAG(F31,Gb,3,1);
        LDFRAG(B00,Tb,0,0); LDFRAG(B01,Tb,0,1); LDFRAG(B10,Tb,1,0); LDFRAG(B11,Tb,1,1);
        LDFRAG(B20,Tb,2,0); LDFRAG(B21,Tb,2,1); LDFRAG(B30,Tb,3,0); LDFRAG(B31,Tb,3,1);
        #undef LDFRAG
    }

    // ---- phase 3: ballot-pack y into LDS words (all 16 rows) ----
    unsigned long long* yball = (unsigned long long*)(SM + OFF_YB);
    #pragma unroll
    for (int q = 0; q < 16; q++) {
        const int* yr = y + (size_t)(R0 + q) * TLEN;
        #pragma unroll
        for (int w = 0; w < 16; w++) {
            const unsigned long long bal = __ballot(yr[w*64 + lane] != 0);
            if (lane == 0) yball[q*16 + w] = bal;
        }
    }

    // ---- phase 4: per-lane bit-streams for BOTH chains -> per-lane LDS ----
    // F stream bit s: y[s+1] (s=0..510); B stream bit s: y[1022-s]
    unsigned long long* ybsF = (unsigned long long*)(SM + OFF_YSF);
    unsigned long long* ybsB = (unsigned long long*)(SM + OFF_YSB);
    int initF, initB;
    {
        unsigned long long rawF[8], rawB[8];
        #pragma unroll
        for (int w = 0; w < 8; w++) {
            rawF[w] = yball[lr*16 + w];
            rawB[w] = __brevll(yball[lr*16 + (15-w)]);
        }
        initF = (int)(rawF[0] & 1ull);            // y[0]
        initB = (int)(rawB[0] & 1ull);            // y[1023]
        #pragma unroll
        for (int w = 0; w < 7; w++) {
            ybsF[w*64 + lane] = (rawF[w] >> 1) | (rawF[w+1] << 63);
            ybsB[w*64 + lane] = (rawB[w] >> 1) | (rawB[w+1] << 63);
        }
        ybsF[7*64 + lane] = rawF[7] >> 1;
        ybsB[7*64 + lane] = rawB[7] >> 1;
    }
    // Each lane reads back ONLY its own slots (same-wave write->read).

    const f32x4 e0_0 = *(const f32x4*)(pE +       0 + 4*g);
    const f32x4 e0_1 = *(const f32x4*)(pE +      16 + 4*g);
    const f32x4 e0_2 = *(const f32x4*)(pE +      32 + 4*g);
    const f32x4 e0_3 = *(const f32x4*)(pE +      48 + 4*g);
    const f32x4 e1_0 = *(const f32x4*)(pE + 64 +  0 + 4*g);
    const f32x4 e1_1 = *(const f32x4*)(pE + 64 + 16 + 4*g);
    const f32x4 e1_2 = *(const f32x4*)(pE + 64 + 32 + 4*g);
    const f32x4 e1_3 = *(const f32x4*)(pE + 64 + 48 + 4*g);

    // ---- init both chains ----
    f32x4 dF0,dF1,dF2,dF3, dB0,dB1,dB2,dB3;
    {
        const f32x4 p0 = *(const f32x4*)(piv +  0 + 4*g);
        const f32x4 p1 = *(const f32x4*)(piv + 16 + 4*g);
        const f32x4 p2 = *(const f32x4*)(piv + 32 + 4*g);
        const f32x4 p3 = *(const f32x4*)(piv + 48 + 4*g);
        dF0 = p0 * (initF ? e1_0 : e0_0);         // alpha_0 = piv ⊙ e_{y0}
        dF1 = p1 * (initF ? e1_1 : e0_1);
        dF2 = p2 * (initF ? e1_2 : e0_2);
        dF3 = p3 * (initF ? e1_3 : e0_3);
        dB0 = initB ? e1_0 : e0_0;                // gamma_1023 = e_{y1023}
        dB1 = initB ? e1_1 : e0_1;
        dB2 = initB ? e1_2 : e0_2;
        dB3 = initB ? e1_3 : e0_3;
    }
    PIN4(dF0,dF1,dF2,dF3);
    PIN4(dB0,dB1,dB2,dB3);

    // ---- main loop: 511 steps, both chains interleaved in one wave ----
    f32x4 tF0,tF1,tF2,tF3, tB0,tB1,tB2,tB3;
    #define PACK(b1,b2,d0,d1,d2,d3) \
        u32x4 w1_##b1, w2_##b1; \
        w1_##b1[0] = packpair(d0.x, d0.y);  w1_##b1[1] = packpair(d0.z, d0.w); \
        w1_##b1[2] = packpair(d1.x, d1.y);  w1_##b1[3] = packpair(d1.z, d1.w); \
        w2_##b1[0] = packpair(d2.x, d2.y);  w2_##b1[1] = packpair(d2.z, d2.w); \
        w2_##b1[2] = packpair(d3.x, d3.y);  w2_##b1[3] = packpair(d3.z, d3.w); \
        const bf16x8 b1 = __builtin_bit_cast(bf16x8, w1_##b1); \
        const bf16x8 b2 = __builtin_bit_cast(bf16x8, w2_##b1);
    #define STEP_BODY() { \
        PACK(bF1, bF2, dF0, dF1, dF2, dF3); \
        PACK(bB1, bB2, dB0, dB1, dB2, dB3); \
        tF0 = MFMA(F00, bF1, zero); tF1 = MFMA(F10, bF1, zero); \
        tF2 = MFMA(F20, bF1, zero); tF3 = MFMA(F30, bF1, zero); \
        tB0 = MFMA(B00, bB1, zero); tB1 = MFMA(B10, bB1, zero); \
        tB2 = MFMA(B20, bB1, zero); tB3 = MFMA(B30, bB1, zero); \
        tF0 = MFMA(F01, bF2, tF0);  tF1 = MFMA(F11, bF2, tF1); \
        tF2 = MFMA(F21, bF2, tF2);  tF3 = MFMA(F31, bF2, tF3); \
        tB0 = MFMA(B01, bB2, tB0);  tB1 = MFMA(B11, bB2, tB1); \
        tB2 = MFMA(B21, bB2, tB2);  tB3 = MFMA(B31, bB2, tB3); \
        PIN4(tF0,tF1,tF2,tF3); \
        PIN4(tB0,tB1,tB2,tB3); }
    #define EMIT_F(cond) { \
        const bool yb_ = (cond); \
        dF0 = tF0 * (yb_ ? e1_0 : e0_0); \
        dF1 = tF1 * (yb_ ? e1_1 : e0_1); \
        dF2 = tF2 * (yb_ ? e1_2 : e0_2); \
        dF3 = tF3 * (yb_ ? e1_3 : e0_3); }
    #define EMIT_B(cond) { \
        const bool yb_ = (cond); \
        dB0 = tB0 * (yb_ ? e1_0 : e0_0); \
        dB1 = tB1 * (yb_ ? e1_1 : e0_1); \
        dB2 = tB2 * (yb_ ? e1_2 : e0_2); \
        dB3 = tB3 * (yb_ ? e1_3 : e0_3); }
    #define RENORM(t0,t1,t2,t3,lacc) { \
        float S_ = t0.x+t0.y+t0.z+t0.w + t1.x+t1.y+t1.z+t1.w \
                 + t2.x+t2.y+t2.z+t2.w + t3.x+t3.y+t3.z+t3.w; \
        S_ += __shfl_xor(S_, 16); \
        S_ += __shfl_xor(S_, 32); \
        lacc += __logf(S_); \
        const float rn_ = __builtin_amdgcn_rcpf(S_); \
        t0 *= rn_; t1 *= rn_; t2 *= rn_; t3 *= rn_; }

    float laccF = 0.f, laccB = 0.f;
    // 31 groups x 16 steps = steps 0..495; renorm at step 15 of each group.
    #pragma unroll 1
    for (int grp = 0; grp < 31; ++grp) {
        const unsigned long long cwF = ybsF[((grp >> 2) << 6) + lane];
        const unsigned long long cwB = ybsB[((grp >> 2) << 6) + lane];
        const u32 bitsF = (u32)(cwF >> ((grp & 3) << 4));
        const u32 bitsB = (u32)(cwB >> ((grp & 3) << 4));
        #pragma unroll
        for (int i = 0; i < 16; ++i) {
            STEP_BODY();
            if (i == 15) {                      // renorm every 16 steps
                RENORM(tF0,tF1,tF2,tF3, laccF);
                RENORM(tB0,tB1,tB2,tB3, laccB);
            }
            EMIT_F(((bitsF >> i) & 1u) != 0u);
            EMIT_B(((bitsB >> i) & 1u) != 0u);
        }
    }
    // tail: steps 496..510 (stream bits 48..62 of word 7), rolled
    {
        u32 bitsF = (u32)(ybsF[(7 << 6) + lane] >> 48);
        u32 bitsB = (u32)(ybsB[(7 << 6) + lane] >> 48);
        #pragma unroll 1
        for (int i = 0; i < 15; ++i) {
            STEP_BODY();
            EMIT_F((bitsF & 1u) != 0u);
            EMIT_B((bitsB & 1u) != 0u);
            bitsF >>= 1;
            bitsB >>= 1;
        }
    }

    // ---- fwd bare matvec (no emission) -> abar_512 (reuses bare T^T frags) ----
    {
        PACK(bT1, bT2, dF0, dF1, dF2, dF3);
        tF0 = MFMA(F00, bT1, zero); tF1 = MFMA(F10, bT1, zero);
        tF2 = MFMA(F20, bT1, zero); tF3 = MFMA(F30, bT1, zero);
        tF0 = MFMA(F01, bT2, tF0);  tF1 = MFMA(F11, bT2, tF1);
        tF2 = MFMA(F21, bT2, tF2);  tF3 = MFMA(F31, bT2, tF3);
        PIN4(tF0,tF1,tF2,tF3);
        dF0 = tF0; dF1 = tF1; dF2 = tF2; dF3 = tF3;
    }
    #undef PACK
    #undef STEP_BODY
    #undef EMIT_F
    #undef EMIT_B
    #undef RENORM

    // ---- combine (register-local): logP = laccF+laccB+log(abar . gamma) ----
    {
        float dot = dF0.x*dB0.x + dF0.y*dB0.y + dF0.z*dB0.z + dF0.w*dB0.w
                  + dF1.x*dB1.x + dF1.y*dB1.y + dF1.z*dB1.z + dF1.w*dB1.w
                  + dF2.x*dB2.x + dF2.y*dB2.y + dF2.z*dB2.z + dF2.w*dB2.w
                  + dF3.x*dB3.x + dF3.y*dB3.y + dF3.z*dB3.z + dF3.w*dB3.w;
        dot += __shfl_xor(dot, 16);
        dot += __shfl_xor(dot, 32);
        float lp = laccF + laccB + __logf(dot);
        if (g == 0) {                      // lanes 0..15: reduce over batch
            lp += __shfl_xor(lp, 1);
            lp += __shfl_xor(lp, 2);
            lp += __shfl_xor(lp, 4);
            lp += __shfl_xor(lp, 8);
            if (lr == 0) atomicAdd(out, lp * (1.0f / BATCH));
        }
    }
}

// ---------------------------------------------------------------------------
extern "C" void kernel_launch(void* const* d_in, const int* in_sizes, int n_in,
                              void* d_out, int out_size, void* d_ws, size_t ws_size,
                              hipStream_t stream) {
    const int*   y  = (const int*)  d_in[0];
    const float* T  = (const float*)d_in[1];
    const float* E  = (const float*)d_in[2];
    const float* Pi = (const float*)d_in[3];
    float* out = (float*)d_out;
    (void)d_ws; (void)ws_size; (void)in_sizes; (void)n_in; (void)out_size;

    hipMemsetAsync(out, 0, sizeof(float), stream);
    hipLaunchKernelGGL(hmm_fb, dim3(BATCH/16), dim3(64), 0, stream,
                       y, T, E, Pi, out);
}

// Round 11
// 187.296 us; speedup vs baseline: 1.4790x; 1.4668x over previous
//
#include <hip/hip_runtime.h>
#include <hip/hip_bf16.h>
#include <stdint.h>

#define BATCH 4096
#define TLEN  1024
#define MSTR  72     // LDS stride (bf16 elems) for T matrices; 144B keeps b64/b128 alignment
#define CSTR  68     // combine buffer stride (f32); 272B keeps f32x4 alignment

// ---- LDS layout (bytes) ----
#define OFF_T    0        // A_B = D(e0)*T   plain [64][MSTR] bf16   (bwd A source)
#define OFF_G    9216     // A_F = D(e0)*T^T row-major               (fwd A source)
#define OFF_PE   18432    // float pE[2][64]
#define OFF_PIV  18944    // float piv[64]
#define OFF_YB   19200    // u64 yball[16][16] = 2048
#define OFF_CMB  21376    // float gamma[16][CSTR]
#define OFF_LACB 25728    // float laccB[16]
#define OFF_YS   25792    // u64 ybsL[2 waves][8 words][64 lanes] = 8192
#define SMEM_SZ  33984

typedef short        bf16x4 __attribute__((ext_vector_type(4)));
typedef short        bf16x8 __attribute__((ext_vector_type(8)));
typedef float        f32x4  __attribute__((ext_vector_type(4)));
typedef unsigned int u32;
typedef unsigned int u32x4  __attribute__((ext_vector_type(4)));

#define MFMA(a,b,c) __builtin_amdgcn_mfma_f32_16x16x32_bf16(a,b,c,0,0,0)

// Hardware packed f32->2xbf16 (RNE), proven in round 7.
static __device__ __forceinline__ u32 packpair(float lo, float hi) {
    u32 r;
    asm("v_cvt_pk_bf16_f32 %0, %1, %2" : "=&v"(r) : "v"(lo), "v"(hi));
    return r;
}

// ---------------------------------------------------------------------------
// 256 wgs x 128 thr (2 waves). wg = 16-batch block, BOTH directions:
//   wave0: forward  chain, A_F = D(e0) T^T (sigma-permuted)
//   wave1: backward chain, A_B = D(e0) T   (sigma-permuted)
// ROUND-11 DELTA vs round 7 (best, 124us): emission-0 is FOLDED into the
// A-matrices (row-scale, legal: A-rows = output rows shared by all batch
// cols). The per-step emission then reduces to a conditional elementwise
// multiply by r = e1/e0 when the lane's y-bit is 1. Since the bit is
// per-lane-uniform over the lane's 16 values, this is done with an
// exec-masked asm block (v_cmp + s_and_saveexec + 16 v_mul + restore =
// ~19 ops) instead of 16 cndmask + 16 mul (32 ops). r9/r10 proved per-wave
// time is proportional to instruction count (~8.7 cy/instr, independence
// doesn't help), so -14 ops/step is the prediction -~24%.
// Fwd bare tail fixes up with a one-time ⊙ 1/e0 (abar = D(e0)^-1 A_F a).
// Everything else byte-identical round 7.
// ---------------------------------------------------------------------------
__global__ __launch_bounds__(128, 1) void hmm_fb(
    const int* __restrict__ y, const float* __restrict__ Tmat,
    const float* __restrict__ Emat, const float* __restrict__ Pi,
    float* __restrict__ out)
{
    __shared__ __align__(16) unsigned char SM[SMEM_SZ];

    const int tid  = threadIdx.x;
    const int wv   = tid >> 6;          // 0 = fwd, 1 = bwd
    const int lane = tid & 63;
    const int lr   = lane & 15;         // batch col
    const int g    = lane >> 4;         // k-group
    const int R0   = blockIdx.x << 4;

    float* pE  = (float*)(SM + OFF_PE);
    float* piv = (float*)(SM + OFF_PIV);
    const f32x4 zero = {0.f, 0.f, 0.f, 0.f};

    // ---- phase 0: emission + pi softmax ----
    if (tid < 64) {
        const float e0 = Emat[tid*2+0], e1 = Emat[tid*2+1];
        const float em = fmaxf(e0, e1);
        const float p0 = __expf(e0-em), p1 = __expf(e1-em);
        const float ez = 1.0f / (p0 + p1);
        pE[tid]      = p0 * ez;
        pE[64 + tid] = p1 * ez;
        float v = Pi[tid];
        float mx = v;
        #pragma unroll
        for (int d = 1; d < 64; d <<= 1) mx = fmaxf(mx, __shfl_xor(mx, d));
        const float e = __expf(v - mx);
        float z = e;
        #pragma unroll
        for (int d = 1; d < 64; d <<= 1) z += __shfl_xor(z, d);
        piv[tid] = e / z;
    }
    __syncthreads();   // phase 1 reads pE (round-5/8-proven ordering)

    // ---- phase 1: row-softmax of T -> e0-scaled plain + transposed bf16 ----
    {
        const int r  = tid >> 1;          // 0..63
        const int hh = tid & 1;           // 32-col half
        float v[32];
        #pragma unroll
        for (int q = 0; q < 8; q++) {
            const float4 t4 = *(const float4*)(Tmat + r*64 + hh*32 + q*4);
            v[q*4+0]=t4.x; v[q*4+1]=t4.y; v[q*4+2]=t4.z; v[q*4+3]=t4.w;
        }
        float mx = v[0];
        #pragma unroll
        for (int k = 1; k < 32; k++) mx = fmaxf(mx, v[k]);
        mx = fmaxf(mx, __shfl_xor(mx, 1));
        float z = 0.f;
        #pragma unroll
        for (int k = 0; k < 32; k++) { v[k] = __expf(v[k]-mx); z += v[k]; }
        z += __shfl_xor(z, 1);
        const float inv = 1.0f / z;
        const float er0 = pE[r];          // row scale for A_B
        __hip_bfloat16* Tsm = (__hip_bfloat16*)(SM + OFF_T);
        __hip_bfloat16* Gt  = (__hip_bfloat16*)(SM + OFF_G);
        #pragma unroll
        for (int k = 0; k < 32; k++) {
            const int j = hh*32 + k;
            const float tval = v[k] * inv;
            Tsm[r*MSTR + j] = __float2bfloat16(er0 * tval);      // A_B[r][j]=e0[r]T[r][j]
            Gt[j*MSTR + r]  = __float2bfloat16(tval * pE[j]);    // A_F[j][r]=e0[j]T[r][j]
        }
    }
    __syncthreads();

    // ---- phase 2: gather permuted A-fragments (register-resident) ----
    // A[m][h] element j (lane g): col sigma = 32h + 4g + (j&3) + 16*(j>>2)
    bf16x8 A00,A01,A10,A11,A20,A21,A30,A31;
    {
        const __hip_bfloat16* Abase =
            (const __hip_bfloat16*)(SM + (wv == 0 ? OFF_G : OFF_T));
        #define LDFRAG(dst, m, h) { \
            const __hip_bfloat16* p_ = Abase + ((m)*16+lr)*MSTR + 32*(h) + 4*g; \
            bf16x4 lo_ = *(const bf16x4*)(p_); \
            bf16x4 hi_ = *(const bf16x4*)(p_ + 16); \
            dst[0]=lo_[0]; dst[1]=lo_[1]; dst[2]=lo_[2]; dst[3]=lo_[3]; \
            dst[4]=hi_[0]; dst[5]=hi_[1]; dst[6]=hi_[2]; dst[7]=hi_[3]; \
        }
        LDFRAG(A00,0,0); LDFRAG(A01,0,1); LDFRAG(A10,1,0); LDFRAG(A11,1,1);
        LDFRAG(A20,2,0); LDFRAG(A21,2,1); LDFRAG(A30,3,0); LDFRAG(A31,3,1);
        #undef LDFRAG
    }

    // ---- phase 3: ballot-pack y into LDS words ----
    unsigned long long* yball = (unsigned long long*)(SM + OFF_YB);
    #pragma unroll
    for (int q = 0; q < 8; q++) {
        const int row = wv*8 + q;
        const int* yr = y + (size_t)(R0 + row) * TLEN;
        #pragma unroll
        for (int w = 0; w < 16; w++) {
            const unsigned long long bal = __ballot(yr[w*64 + lane] != 0);
            if (lane == 0) yball[row*16 + w] = bal;
        }
    }
    __syncthreads();

    // ---- phase 4: per-lane bit-streams -> per-lane LDS slots ----
    // stream bit s: fwd -> y[s+1] (s=0..510); bwd -> y[1022-s]
    unsigned long long* ybsL = (unsigned long long*)(SM + OFF_YS) + wv*(8*64);
    int initbit;
    {
        unsigned long long raw[8];
        if (wv == 0) {
            #pragma unroll
            for (int w = 0; w < 8; w++) raw[w] = yball[lr*16 + w];
        } else {
            #pragma unroll
            for (int w = 0; w < 8; w++) raw[w] = __brevll(yball[lr*16 + (15-w)]);
        }
        initbit = (int)(raw[0] & 1ull);           // fwd: y[0]; bwd: y[1023]
        #pragma unroll
        for (int w = 0; w < 7; w++)
            ybsL[w*64 + lane] = (raw[w] >> 1) | (raw[w+1] << 63);
        ybsL[7*64 + lane] = raw[7] >> 1;
    }
    // Each lane reads back ONLY its own ybsL slots (same-wave write->read).

    // ---- init; then derive r = e1/e0 and iv = 1/e0 (e regs die after) ----
    f32x4 d0, d1, d2, d3, rr0, rr1, rr2, rr3, iv0, iv1, iv2, iv3;
    {
        const f32x4 e0_0 = *(const f32x4*)(pE +       0 + 4*g);
        const f32x4 e0_1 = *(const f32x4*)(pE +      16 + 4*g);
        const f32x4 e0_2 = *(const f32x4*)(pE +      32 + 4*g);
        const f32x4 e0_3 = *(const f32x4*)(pE +      48 + 4*g);
        const f32x4 e1_0 = *(const f32x4*)(pE + 64 +  0 + 4*g);
        const f32x4 e1_1 = *(const f32x4*)(pE + 64 + 16 + 4*g);
        const f32x4 e1_2 = *(const f32x4*)(pE + 64 + 32 + 4*g);
        const f32x4 e1_3 = *(const f32x4*)(pE + 64 + 48 + 4*g);
        if (wv == 0) {                        // alpha_0 = piv ⊙ e_{y0}
            const f32x4 p0 = *(const f32x4*)(piv +  0 + 4*g);
            const f32x4 p1 = *(const f32x4*)(piv + 16 + 4*g);
            const f32x4 p2 = *(const f32x4*)(piv + 32 + 4*g);
            const f32x4 p3 = *(const f32x4*)(piv + 48 + 4*g);
            d0 = p0 * (initbit ? e1_0 : e0_0);
            d1 = p1 * (initbit ? e1_1 : e0_1);
            d2 = p2 * (initbit ? e1_2 : e0_2);
            d3 = p3 * (initbit ? e1_3 : e0_3);
        } else {                              // gamma_1023 = e_{y1023}
            d0 = initbit ? e1_0 : e0_0;
            d1 = initbit ? e1_1 : e0_1;
            d2 = initbit ? e1_2 : e0_2;
            d3 = initbit ? e1_3 : e0_3;
        }
        #define RCP4(dst, src) { \
            dst.x = __builtin_amdgcn_rcpf(src.x); \
            dst.y = __builtin_amdgcn_rcpf(src.y); \
            dst.z = __builtin_amdgcn_rcpf(src.z); \
            dst.w = __builtin_amdgcn_rcpf(src.w); }
        RCP4(iv0, e0_0); RCP4(iv1, e0_1); RCP4(iv2, e0_2); RCP4(iv3, e0_3);
        #undef RCP4
        rr0 = e1_0 * iv0;  rr1 = e1_1 * iv1;
        rr2 = e1_2 * iv2;  rr3 = e1_3 * iv3;
    }

    // ---- main loop: 511 register-only steps ----
    #define STEP_MM() { \
        u32x4 w1_, w2_; \
        w1_[0] = packpair(d0.x, d0.y);  w1_[1] = packpair(d0.z, d0.w); \
        w1_[2] = packpair(d1.x, d1.y);  w1_[3] = packpair(d1.z, d1.w); \
        w2_[0] = packpair(d2.x, d2.y);  w2_[1] = packpair(d2.z, d2.w); \
        w2_[2] = packpair(d3.x, d3.y);  w2_[3] = packpair(d3.z, d3.w); \
        const bf16x8 b1 = __builtin_bit_cast(bf16x8, w1_); \
        const bf16x8 b2 = __builtin_bit_cast(bf16x8, w2_); \
        d0 = MFMA(A00, b1, zero); d1 = MFMA(A10, b1, zero); \
        d2 = MFMA(A20, b1, zero); d3 = MFMA(A30, b1, zero); \
        d0 = MFMA(A01, b2, d0);   d1 = MFMA(A11, b2, d1); \
        d2 = MFMA(A21, b2, d2);   d3 = MFMA(A31, b2, d3); \
    }
    // exec-masked conditional multiply: lanes with pred!=0 do d *= r.
    #define CONDMUL(predexpr) { \
        const u32 pred_ = (u32)(predexpr); \
        float a0_=d0.x,a1_=d0.y,a2_=d0.z,a3_=d0.w; \
        float a4_=d1.x,a5_=d1.y,a6_=d1.z,a7_=d1.w; \
        float a8_=d2.x,a9_=d2.y,a10_=d2.z,a11_=d2.w; \
        float a12_=d3.x,a13_=d3.y,a14_=d3.z,a15_=d3.w; \
        unsigned long long sv_; \
        asm("v_cmp_ne_u32 vcc, 0, %[p]\n\t" \
            "s_and_saveexec_b64 %[sv], vcc\n\t" \
            "v_mul_f32 %[a0], %[a0], %[q0]\n\t" \
            "v_mul_f32 %[a1], %[a1], %[q1]\n\t" \
            "v_mul_f32 %[a2], %[a2], %[q2]\n\t" \
            "v_mul_f32 %[a3], %[a3], %[q3]\n\t" \
            "v_mul_f32 %[a4], %[a4], %[q4]\n\t" \
            "v_mul_f32 %[a5], %[a5], %[q5]\n\t" \
            "v_mul_f32 %[a6], %[a6], %[q6]\n\t" \
            "v_mul_f32 %[a7], %[a7], %[q7]\n\t" \
            "v_mul_f32 %[a8], %[a8], %[q8]\n\t" \
            "v_mul_f32 %[a9], %[a9], %[q9]\n\t" \
            "v_mul_f32 %[a10], %[a10], %[q10]\n\t" \
            "v_mul_f32 %[a11], %[a11], %[q11]\n\t" \
            "v_mul_f32 %[a12], %[a12], %[q12]\n\t" \
            "v_mul_f32 %[a13], %[a13], %[q13]\n\t" \
            "v_mul_f32 %[a14], %[a14], %[q14]\n\t" \
            "v_mul_f32 %[a15], %[a15], %[q15]\n\t" \
            "s_mov_b64 exec, %[sv]" \
            : [sv]"=s"(sv_), \
              [a0]"+v"(a0_),[a1]"+v"(a1_),[a2]"+v"(a2_),[a3]"+v"(a3_), \
              [a4]"+v"(a4_),[a5]"+v"(a5_),[a6]"+v"(a6_),[a7]"+v"(a7_), \
              [a8]"+v"(a8_),[a9]"+v"(a9_),[a10]"+v"(a10_),[a11]"+v"(a11_), \
              [a12]"+v"(a12_),[a13]"+v"(a13_),[a14]"+v"(a14_),[a15]"+v"(a15_) \
            : [p]"v"(pred_), \
              [q0]"v"(rr0.x),[q1]"v"(rr0.y),[q2]"v"(rr0.z),[q3]"v"(rr0.w), \
              [q4]"v"(rr1.x),[q5]"v"(rr1.y),[q6]"v"(rr1.z),[q7]"v"(rr1.w), \
              [q8]"v"(rr2.x),[q9]"v"(rr2.y),[q10]"v"(rr2.z),[q11]"v"(rr2.w), \
              [q12]"v"(rr3.x),[q13]"v"(rr3.y),[q14]"v"(rr3.z),[q15]"v"(rr3.w) \
            : "vcc", "scc"); \
        d0.x=a0_; d0.y=a1_; d0.z=a2_; d0.w=a3_; \
        d1.x=a4_; d1.y=a5_; d1.z=a6_; d1.w=a7_; \
        d2.x=a8_; d2.y=a9_; d2.z=a10_; d2.w=a11_; \
        d3.x=a12_; d3.y=a13_; d3.z=a14_; d3.w=a15_; \
    }
    #define RENORM() { \
        float S_ = d0.x+d0.y+d0.z+d0.w + d1.x+d1.y+d1.z+d1.w \
                 + d2.x+d2.y+d2.z+d2.w + d3.x+d3.y+d3.z+d3.w; \
        S_ += __shfl_xor(S_, 16); \
        S_ += __shfl_xor(S_, 32); \
        lacc += __logf(S_); \
        const float rn_ = __builtin_amdgcn_rcpf(S_); \
        d0 *= rn_; d1 *= rn_; d2 *= rn_; d3 *= rn_; \
    }

    float lacc = 0.f;
    // 31 groups x 16 steps = steps 0..495; renorm at step 15 of each group.
    #pragma unroll 1
    for (int grp = 0; grp < 31; ++grp) {
        const unsigned long long cw = ybsL[((grp >> 2) << 6) + lane];
        const u32 bits = (u32)(cw >> ((grp & 3) << 4));
        #pragma unroll
        for (int i = 0; i < 16; ++i) {
            STEP_MM();
            if (i == 15) { RENORM(); }
            CONDMUL(bits & (1u << i));
        }
    }
    // tail: steps 496..510 (stream bits 48..62 of word 7), rolled
    {
        u32 bits = (u32)(ybsL[(7 << 6) + lane] >> 48);
        #pragma unroll 1
        for (int i = 0; i < 15; ++i) {
            STEP_MM();
            CONDMUL(bits & 1u);
            bits >>= 1;
        }
    }

    // ---- fwd: bare matvec -> abar_512 = D(e0)^-1 * (A_F alpha_511) ----
    if (wv == 0) {
        STEP_MM();
        d0 = d0 * iv0; d1 = d1 * iv1; d2 = d2 * iv2; d3 = d3 * iv3;
    }
    #undef STEP_MM
    #undef CONDMUL
    #undef RENORM

    // ---- combine: logP = laccF + laccB + log(abar_512 . gamma_512) ----
    if (wv == 1) {
        float* CB = (float*)(SM + OFF_CMB);
        *(f32x4*)(CB + lr*CSTR +  0 + 4*g) = d0;
        *(f32x4*)(CB + lr*CSTR + 16 + 4*g) = d1;
        *(f32x4*)(CB + lr*CSTR + 32 + 4*g) = d2;
        *(f32x4*)(CB + lr*CSTR + 48 + 4*g) = d3;
        if (lane < 16) ((float*)(SM + OFF_LACB))[lane] = lacc;
    }
    __syncthreads();
    if (wv == 0) {
        const float* CB = (const float*)(SM + OFF_CMB);
        const f32x4 q0 = *(const f32x4*)(CB + lr*CSTR +  0 + 4*g);
        const f32x4 q1 = *(const f32x4*)(CB + lr*CSTR + 16 + 4*g);
        const f32x4 q2 = *(const f32x4*)(CB + lr*CSTR + 32 + 4*g);
        const f32x4 q3 = *(const f32x4*)(CB + lr*CSTR + 48 + 4*g);
        float dot = d0.x*q0.x + d0.y*q0.y + d0.z*q0.z + d0.w*q0.w
                  + d1.x*q1.x + d1.y*q1.y + d1.z*q1.z + d1.w*q1.w
                  + d2.x*q2.x + d2.y*q2.y + d2.z*q2.z + d2.w*q2.w
                  + d3.x*q3.x + d3.y*q3.y + d3.z*q3.z + d3.w*q3.w;
        dot += __shfl_xor(dot, 16);
        dot += __shfl_xor(dot, 32);
        float lp = lacc + ((const float*)(SM + OFF_LACB))[lr] + __logf(dot);
        if (g == 0) {                      // lanes 0..15: reduce over batch
            lp += __shfl_xor(lp, 1);
            lp += __shfl_xor(lp, 2);
            lp += __shfl_xor(lp, 4);
            lp += __shfl_xor(lp, 8);
            if (lr == 0) atomicAdd(out, lp * (1.0f / BATCH));
        }
    }
}

// ---------------------------------------------------------------------------
extern "C" void kernel_launch(void* const* d_in, const int* in_sizes, int n_in,
                              void* d_out, int out_size, void* d_ws, size_t ws_size,
                              hipStream_t stream) {
    const int*   y  = (const int*)  d_in[0];
    const float* T  = (const float*)d_in[1];
    const float* E  = (const float*)d_in[2];
    const float* Pi = (const float*)d_in[3];
    float* out = (float*)d_out;
    (void)d_ws; (void)ws_size; (void)in_sizes; (void)n_in; (void)out_size;

    hipMemsetAsync(out, 0, sizeof(float), stream);
    hipLaunchKernelGGL(hmm_fb, dim3(BATCH/16), dim3(128), 0, stream,
                       y, T, E, Pi, out);
}